// Round 6
// baseline (37094.528 us; speedup 1.0000x reference)
//
#include <hip/hip_runtime.h>
#include <hip/hip_cooperative_groups.h>
#include <math.h>

namespace cg = cooperative_groups;

#define BB 64
#define SS 512
#define INF 64
#define HH 512
#define G5 2560

// ---------------- init: zero recurrent state ----------------
__global__ void init_kernel(float* __restrict__ p, int n) {
    int i = blockIdx.x * blockDim.x + threadIdx.x;
    if (i < n) p[i] = 0.f;
}

// ---------------- weight repack (per call; LDS-tiled transpose) ----------------
// P[(g*20 + gate*4 + c)*K + k] = W[k*G5 + gate*512 + g*4 + c]
__global__ __launch_bounds__(256) void repack_kernel(
    const float* __restrict__ W, float* __restrict__ P, int K)
{
    __shared__ float tile[64][65];
    const int tid = threadIdx.x;
    const int kt = blockIdx.x;
    const int c0 = blockIdx.y * 64;

    for (int e = tid; e < 64 * 16; e += 256) {
        int kr = e >> 4, cq = (e & 15) * 4;
        float4 v = *(const float4*)(W + (size_t)(kt * 64 + kr) * G5 + c0 + cq);
        tile[kr][cq + 0] = v.x; tile[kr][cq + 1] = v.y;
        tile[kr][cq + 2] = v.z; tile[kr][cq + 3] = v.w;
    }
    __syncthreads();

    const int gate  = c0 >> 9;
    const int gbase = (c0 & 511) >> 2;
    for (int e = tid; e < 64 * 16; e += 256) {
        int lr = e >> 4;
        int kq = (e & 15) * 4;
        int g  = gbase + (lr >> 2);
        int c  = lr & 3;
        int orow = g * 20 + gate * 4 + c;
        float4 v;
        v.x = tile[kq + 0][lr]; v.y = tile[kq + 1][lr];
        v.z = tile[kq + 2][lr]; v.w = tile[kq + 3][lr];
        *(float4*)(P + (size_t)orow * K + kt * 64 + kq) = v;
    }
}

// ---------------- x transpose: xT[t][k][row] = x[row][t][k] ----------------
__global__ __launch_bounds__(256) void xpose_kernel(
    const float* __restrict__ x, float* __restrict__ xT)
{
    __shared__ float tile[64][68];
    const int tid = threadIdx.x;
    const int t = blockIdx.x;

    for (int e = tid; e < 64 * 16; e += 256) {
        int row = e >> 4, kq = (e & 15) * 4;
        float4 v = *(const float4*)(x + ((size_t)row * SS + t) * INF + kq);
        tile[row][kq + 0] = v.x; tile[row][kq + 1] = v.y;
        tile[row][kq + 2] = v.z; tile[row][kq + 3] = v.w;
    }
    __syncthreads();
    for (int e = tid; e < 64 * 16; e += 256) {
        int k = e >> 4, rq = (e & 15) * 4;
        float4 v;
        v.x = tile[rq + 0][k]; v.y = tile[rq + 1][k];
        v.z = tile[rq + 2][k]; v.w = tile[rq + 3][k];
        *(float4*)(xT + ((size_t)t * INF + k) * BB + rq) = v;
    }
}

// ---------------- persistent recurrence kernel (all 513 steps) ----------------
// blocks 0..127: L0 ; blocks 128..255: L1 (runs step t-1)
// W broadcast from repacked global P (XCD-L2 resident); state [k][row].
__global__ __launch_bounds__(256, 1) void persist_kernel(
    const float* __restrict__ xT,
    const float* __restrict__ P0, const float* __restrict__ b0v,
    const float* __restrict__ P1, const float* __restrict__ b1v,
    float* __restrict__ h0buf, float* __restrict__ h1buf,
    float* __restrict__ c0buf, float* __restrict__ c1buf,
    float* __restrict__ lstm_out)
{
    __shared__ float red[4][20][64];          // 20 KB

    cg::grid_group grid = cg::this_grid();

    const int tid  = threadIdx.x;
    const int lane = tid & 63;          // batch row
    const int wv   = tid >> 6;          // K-quarter / epilogue column
    const bool isL1 = (blockIdx.x >= 128);
    const int blk  = isL1 ? ((int)blockIdx.x - 128) : (int)blockIdx.x;
    const int g    = (blk & 7) * 16 + (blk >> 3);   // XCD-pinned col group
    const int j    = g * 4 + wv;

    const int K  = isL1 ? 1024 : 576;
    const int QK = K >> 2;              // 256 or 144
    const int NQ = QK >> 2;             // 64 or 36 quads (even)
    const int k0 = wv * QK;

    const float* Pg = (isL1 ? P1 : P0) + (size_t)g * 20 * K;
    const float* wrow[20];
    #pragma unroll
    for (int r = 0; r < 20; ++r) wrow[r] = Pg + (size_t)r * K;

    const float* bv = isL1 ? b1v : b0v;
    float bias[5];
    #pragma unroll
    for (int gate = 0; gate < 5; ++gate) bias[gate] = bv[gate * HH + j];

    float* cptr = (isL1 ? c1buf : c0buf) + j * BB + lane;

    for (int t = 0; t <= SS; ++t) {
        const bool active = isL1 ? (t >= 1) : (t < SS);
        if (active) {
            const int tm1 = t - 1;
            const float* h0prev = h0buf + ((t + 1) & 1) * (BB * HH);
            const float* h0cur  = h0buf + (tm1 & 1) * (BB * HH);
            const float* h1prev = h1buf + ((tm1 + 1) & 1) * (BB * HH);

            float acc[20];
            #pragma unroll
            for (int r = 0; r < 20; ++r) acc[r] = 0.f;

            auto loadA = [&](int q, float* a) {
                int k = k0 + 4 * q;
                const float* s;
                if (!isL1) {
                    if (k < INF) s = xT + ((size_t)t * INF + k) * BB;
                    else         s = h0prev + (size_t)(k - INF) * BB;
                } else {
                    if (k < HH)  s = h0cur + (size_t)k * BB;
                    else         s = h1prev + (size_t)(k - HH) * BB;
                }
                a[0] = s[0 * BB + lane];
                a[1] = s[1 * BB + lane];
                a[2] = s[2 * BB + lane];
                a[3] = s[3 * BB + lane];
            };
            auto loadW = [&](int q, float4* w) {
                int k = k0 + 4 * q;
                #pragma unroll
                for (int r = 0; r < 20; ++r)
                    w[r] = *(const float4*)(wrow[r] + k);
            };

            float4 wA[20], wB[20];
            float aA[4], aB[4];
            loadA(0, aA); loadW(0, wA);

            for (int q = 0; q < NQ; q += 2) {
                loadA(q + 1, aB); loadW(q + 1, wB);
                #pragma unroll
                for (int r = 0; r < 20; ++r) {
                    acc[r] = fmaf(aA[0], wA[r].x, acc[r]);
                    acc[r] = fmaf(aA[1], wA[r].y, acc[r]);
                    acc[r] = fmaf(aA[2], wA[r].z, acc[r]);
                    acc[r] = fmaf(aA[3], wA[r].w, acc[r]);
                }
                if (q + 2 < NQ) { loadA(q + 2, aA); loadW(q + 2, wA); }
                #pragma unroll
                for (int r = 0; r < 20; ++r) {
                    acc[r] = fmaf(aB[0], wB[r].x, acc[r]);
                    acc[r] = fmaf(aB[1], wB[r].y, acc[r]);
                    acc[r] = fmaf(aB[2], wB[r].z, acc[r]);
                    acc[r] = fmaf(aB[3], wB[r].w, acc[r]);
                }
            }

            // ---- cross-wave K reduction ----
            #pragma unroll
            for (int r = 0; r < 20; ++r) red[wv][r][lane] = acc[r];
            __syncthreads();

            float gv[5];
            #pragma unroll
            for (int gate = 0; gate < 5; ++gate) {
                int r = gate * 4 + wv;
                gv[gate] = red[0][r][lane] + red[1][r][lane]
                         + red[2][r][lane] + red[3][r][lane] + bias[gate];
            }

            float f  = 1.f / (1.f + expf(-gv[0]));
            float i_ = 1.f / (1.f + expf(-gv[1]));
            float ch = tanhf(gv[2]);
            float o  = 1.f / (1.f + expf(-gv[3]));
            float e_ = 1.f / (1.f + expf(-gv[4]));

            float c = f * (*cptr) + i_ * ch;
            *cptr = c;
            float hl = o * tanhf(c);
            float hn = e_ * expf(hl) + (1.f - e_) * hl;

            if (!isL1) {
                h0buf[(t & 1) * (BB * HH) + j * BB + lane] = hn;
            } else {
                h1buf[(tm1 & 1) * (BB * HH) + j * BB + lane] = hn;
                lstm_out[((size_t)lane * SS + tm1) * HH + j] = hn;
            }
            __syncthreads();   // protect red[] before next phase
        }
        grid.sync();
    }
}

// ---------------- fallback per-step kernel (R4-verified) ----------------
// blocks 0..127: L0 step t ; 128..255: L1 step t-1. State [k][row], x = xT.
__global__ __launch_bounds__(256) void step_kernel(
    const float* __restrict__ xT,
    const float* __restrict__ P0, const float* __restrict__ b0v,
    const float* __restrict__ P1, const float* __restrict__ b1v,
    float* __restrict__ h0buf, float* __restrict__ h1buf,
    float* __restrict__ c0buf, float* __restrict__ c1buf,
    float* __restrict__ lstm_out, int t)
{
    __shared__ float red[4][20][64];

    const int tid  = threadIdx.x;
    const int lane = tid & 63;
    const int wv   = tid >> 6;
    const bool isL1 = (blockIdx.x >= 128);
    const int blk  = isL1 ? ((int)blockIdx.x - 128) : (int)blockIdx.x;
    const int g    = (blk & 7) * 16 + (blk >> 3);
    const int j    = g * 4 + wv;

    if (!isL1 && t >= SS) return;
    if (isL1 && t == 0) return;

    const int tm1 = t - 1;
    const float* h0prev = h0buf + ((t + 1) & 1) * (BB * HH);
    const float* h0cur  = h0buf + (tm1 & 1) * (BB * HH);
    const float* h1prev = h1buf + ((tm1 + 1) & 1) * (BB * HH);

    const int K  = isL1 ? 1024 : 576;
    const int QK = K >> 2;
    const int NQ = QK >> 2;
    const int k0 = wv * QK;

    const float* Pg = (isL1 ? P1 : P0) + (size_t)g * 20 * K;
    const float* wrow[20];
    #pragma unroll
    for (int r = 0; r < 20; ++r) wrow[r] = Pg + (size_t)r * K;

    float acc[20];
    #pragma unroll
    for (int r = 0; r < 20; ++r) acc[r] = 0.f;

    auto loadA = [&](int q, float* a) {
        int k = k0 + 4 * q;
        const float* s;
        if (!isL1) {
            if (k < INF) s = xT + ((size_t)t * INF + k) * BB;
            else         s = h0prev + (size_t)(k - INF) * BB;
        } else {
            if (k < HH)  s = h0cur + (size_t)k * BB;
            else         s = h1prev + (size_t)(k - HH) * BB;
        }
        a[0] = s[0 * BB + lane];
        a[1] = s[1 * BB + lane];
        a[2] = s[2 * BB + lane];
        a[3] = s[3 * BB + lane];
    };
    auto loadW = [&](int q, float4* w) {
        int k = k0 + 4 * q;
        #pragma unroll
        for (int r = 0; r < 20; ++r)
            w[r] = *(const float4*)(wrow[r] + k);
    };

    float4 wA[20], wB[20];
    float aA[4], aB[4];
    loadA(0, aA); loadW(0, wA);

    for (int q = 0; q < NQ; q += 2) {
        loadA(q + 1, aB); loadW(q + 1, wB);
        #pragma unroll
        for (int r = 0; r < 20; ++r) {
            acc[r] = fmaf(aA[0], wA[r].x, acc[r]);
            acc[r] = fmaf(aA[1], wA[r].y, acc[r]);
            acc[r] = fmaf(aA[2], wA[r].z, acc[r]);
            acc[r] = fmaf(aA[3], wA[r].w, acc[r]);
        }
        if (q + 2 < NQ) { loadA(q + 2, aA); loadW(q + 2, wA); }
        #pragma unroll
        for (int r = 0; r < 20; ++r) {
            acc[r] = fmaf(aB[0], wB[r].x, acc[r]);
            acc[r] = fmaf(aB[1], wB[r].y, acc[r]);
            acc[r] = fmaf(aB[2], wB[r].z, acc[r]);
            acc[r] = fmaf(aB[3], wB[r].w, acc[r]);
        }
    }

    #pragma unroll
    for (int r = 0; r < 20; ++r) red[wv][r][lane] = acc[r];
    __syncthreads();

    const float* bv = isL1 ? b1v : b0v;
    float gv[5];
    #pragma unroll
    for (int gate = 0; gate < 5; ++gate) {
        int r = gate * 4 + wv;
        gv[gate] = red[0][r][lane] + red[1][r][lane]
                 + red[2][r][lane] + red[3][r][lane] + bv[gate * HH + j];
    }

    float f  = 1.f / (1.f + expf(-gv[0]));
    float i_ = 1.f / (1.f + expf(-gv[1]));
    float ch = tanhf(gv[2]);
    float o  = 1.f / (1.f + expf(-gv[3]));
    float e_ = 1.f / (1.f + expf(-gv[4]));

    float* cptr = (isL1 ? c1buf : c0buf) + j * BB + lane;
    float c = f * (*cptr) + i_ * ch;
    *cptr = c;
    float hl = o * tanhf(c);
    float hn = e_ * expf(hl) + (1.f - e_) * hl;

    if (!isL1) {
        h0buf[(t & 1) * (BB * HH) + j * BB + lane] = hn;
    } else {
        h1buf[(tm1 & 1) * (BB * HH) + j * BB + lane] = hn;
        lstm_out[((size_t)lane * SS + tm1) * HH + j] = hn;
    }
}

// ---------------- attention epilogue, one block per batch row ----------------
__global__ __launch_bounds__(256) void attn_kernel(
    const float* __restrict__ lstm_out,
    const float* __restrict__ Wa, const float* __restrict__ ba,
    const float* __restrict__ Wfc, const float* __restrict__ bfc,
    float* __restrict__ dout)
{
    const int b = blockIdx.x;
    const int tid = threadIdx.x;
    const int lane = tid & 63;
    const int wave = tid >> 6;

    __shared__ float wa_s[HH];
    __shared__ float logit[SS];
    __shared__ float wred[4];

    for (int ii = tid; ii < HH; ii += 256) wa_s[ii] = Wa[ii];
    __syncthreads();

    const float* Lb = lstm_out + (size_t)b * SS * HH;

    for (int tt = wave; tt < SS; tt += 4) {
        const float* rowp = Lb + (size_t)tt * HH;
        float s = 0.f;
        for (int jc = lane; jc < HH; jc += 64) s += rowp[jc] * wa_s[jc];
        #pragma unroll
        for (int off = 32; off > 0; off >>= 1) s += __shfl_down(s, off, 64);
        if (lane == 0) logit[tt] = s + ba[0];
    }
    __syncthreads();

    float m = -1e30f;
    for (int ii = tid; ii < SS; ii += 256) m = fmaxf(m, logit[ii]);
    #pragma unroll
    for (int off = 32; off > 0; off >>= 1) m = fmaxf(m, __shfl_down(m, off, 64));
    if (lane == 0) wred[wave] = m;
    __syncthreads();
    m = fmaxf(fmaxf(wred[0], wred[1]), fmaxf(wred[2], wred[3]));
    __syncthreads();

    float ssum = 0.f;
    for (int ii = tid; ii < SS; ii += 256) {
        float e = expf(logit[ii] - m);
        logit[ii] = e;
        ssum += e;
    }
    #pragma unroll
    for (int off = 32; off > 0; off >>= 1) ssum += __shfl_down(ssum, off, 64);
    if (lane == 0) wred[wave] = ssum;
    __syncthreads();
    ssum = wred[0] + wred[1] + wred[2] + wred[3];
    float inv = 1.f / ssum;
    __syncthreads();

    for (int ii = tid; ii < SS; ii += 256) {
        float a = logit[ii] * inv;
        logit[ii] = a;
        dout[BB + (size_t)b * SS + ii] = a;
    }
    __syncthreads();

    float ctx0 = 0.f, ctx1 = 0.f;
    for (int tt = 0; tt < SS; ++tt) {
        float a = logit[tt];
        ctx0 += a * Lb[(size_t)tt * HH + tid];
        ctx1 += a * Lb[(size_t)tt * HH + tid + 256];
    }

    float p = ctx0 * Wfc[tid] + ctx1 * Wfc[tid + 256];
    #pragma unroll
    for (int off = 32; off > 0; off >>= 1) p += __shfl_down(p, off, 64);
    __syncthreads();
    if (lane == 0) wred[wave] = p;
    __syncthreads();
    if (tid == 0) dout[b] = wred[0] + wred[1] + wred[2] + wred[3] + bfc[0];
}

extern "C" void kernel_launch(void* const* d_in, const int* in_sizes, int n_in,
                              void* d_out, int out_size, void* d_ws, size_t ws_size,
                              hipStream_t stream) {
    const float* x   = (const float*)d_in[0];
    const float* W0  = (const float*)d_in[1];
    const float* b0  = (const float*)d_in[2];
    const float* W1  = (const float*)d_in[3];
    const float* b1  = (const float*)d_in[4];
    const float* Wa  = (const float*)d_in[5];
    const float* ba  = (const float*)d_in[6];
    const float* Wfc = (const float*)d_in[7];
    const float* bfc = (const float*)d_in[8];
    float* out = (float*)d_out;
    float* ws  = (float*)d_ws;

    float* h0   = ws;                              // 2*H*B
    float* h1   = h0 + 2 * BB * HH;                // 2*H*B
    float* c0   = h1 + 2 * BB * HH;                // H*B
    float* c1   = c0 + BB * HH;                    // H*B
    float* lstm = c1 + BB * HH;                    // B*S*H
    float* P0   = lstm + (size_t)BB * SS * HH;     // 2560*576
    float* P1   = P0 + (size_t)G5 * (INF + HH);    // 2560*1024
    float* xT   = P1 + (size_t)G5 * (HH + HH);     // S*IN*B

    const int state_n = 6 * BB * HH;
    init_kernel<<<(state_n + 255) / 256, 256, 0, stream>>>(ws, state_n);

    repack_kernel<<<dim3((INF + HH) / 64, 40), 256, 0, stream>>>(W0, P0, INF + HH);
    repack_kernel<<<dim3((HH + HH) / 64, 40), 256, 0, stream>>>(W1, P1, HH + HH);
    xpose_kernel<<<SS, 256, 0, stream>>>(x, xT);

    void* args[] = { (void*)&xT, (void*)&P0, (void*)&b0, (void*)&P1, (void*)&b1,
                     (void*)&h0, (void*)&h1, (void*)&c0, (void*)&c1, (void*)&lstm };
    hipError_t cerr = hipLaunchCooperativeKernel((void*)persist_kernel,
                                                 dim3(256), dim3(256),
                                                 args, 0, stream);
    if (cerr != hipSuccess) {
        // fallback: per-step launches (R4-verified structure)
        for (int t = 0; t <= SS; ++t) {
            step_kernel<<<256, 256, 0, stream>>>(xT, P0, b0, P1, b1,
                                                 h0, h1, c0, c1, lstm, t);
        }
    }

    attn_kernel<<<BB, 256, 0, stream>>>(lstm, Wa, ba, Wfc, bfc, out);
}